// Round 3
// baseline (511.468 us; speedup 1.0000x reference)
//
#include <hip/hip_runtime.h>

// Problem constants (match reference)
#define B_SZ   8
#define NUMR   128            // num
#define L_SZ   (NUMR * NUMR)  // 16384
#define HH     8              // heads
#define DK     64
#define CC     512            // H*DK
#define EPSV   1e-8f
#define SROW   (HH + 1)       // LDS row stride 9 -> at most 2-way bank alias (free)

// ---------------------------------------------------------------------------
// Kernel A: cosine similarity + ReLU + fold-in roi + per-(b,i,h) top-4 union.
// One block (512 thr = 8 waves) per (b,i). Each wave handles 16 j-rows in
// groups of 4: all 16 dwordx4 loads of a group are issued before any use
// (explicit register arrays -> deep MLP; vgpr ~100, __launch_bounds__(512,4)
// keeps 2 blocks/CU). The 3-stage 8-lane shuffle reductions for the 4 rows
// are interleaved stage-major so the ds_bpermute latencies overlap.
// Results go to LDS only; after the barrier one coalesced 4 KB store writes
// attn*roi to d_out and the 8 waves do per-head top-4 from LDS, unioning
// winner columns into colmask (racing identical 1.0f stores: benign).
// ---------------------------------------------------------------------------
__global__ __launch_bounds__(512, 4) void cos_topk_kernel(
    const float* __restrict__ q, const float* __restrict__ k,
    const float* __restrict__ roi,
    float* __restrict__ out, float* __restrict__ colmask) {
  __shared__ float sA[NUMR][SROW];

  const int bi   = blockIdx.x;        // b*num + i
  const int wave = threadIdx.x >> 6;  // 0..7
  const int lane = threadIdx.x & 63;

  // lane's 8 floats are columns [lane*8, lane*8+8) of a row -> head lane>>3
  const size_t lanebase =
      (size_t)bi * NUMR * CC + (size_t)wave * 16 * CC + (size_t)lane * 8;

#pragma unroll 1
  for (int t = 0; t < 16; t += 4) {
    float4 a0[4], a1[4], b0[4], b1[4];
#pragma unroll
    for (int u = 0; u < 4; ++u) {
      const size_t rb = lanebase + (size_t)(t + u) * CC;
      const float4* qp = (const float4*)(q + rb);
      const float4* kp = (const float4*)(k + rb);
      a0[u] = qp[0];
      a1[u] = qp[1];
      b0[u] = kp[0];
      b1[u] = kp[1];
    }

    float dt[4], qs[4], ks[4];
#pragma unroll
    for (int u = 0; u < 4; ++u) {
      dt[u] = a0[u].x * b0[u].x + a0[u].y * b0[u].y + a0[u].z * b0[u].z +
              a0[u].w * b0[u].w + a1[u].x * b1[u].x + a1[u].y * b1[u].y +
              a1[u].z * b1[u].z + a1[u].w * b1[u].w;
      qs[u] = a0[u].x * a0[u].x + a0[u].y * a0[u].y + a0[u].z * a0[u].z +
              a0[u].w * a0[u].w + a1[u].x * a1[u].x + a1[u].y * a1[u].y +
              a1[u].z * a1[u].z + a1[u].w * a1[u].w;
      ks[u] = b0[u].x * b0[u].x + b0[u].y * b0[u].y + b0[u].z * b0[u].z +
              b0[u].w * b0[u].w + b1[u].x * b1[u].x + b1[u].y * b1[u].y +
              b1[u].z * b1[u].z + b1[u].w * b1[u].w;
    }

    // stage-major butterfly within each 8-lane head group: 12 independent
    // ds ops per stage -> latency overlapped across the 4 rows
#pragma unroll
    for (int off = 1; off < 8; off <<= 1) {
#pragma unroll
      for (int u = 0; u < 4; ++u) {
        dt[u] += __shfl_xor(dt[u], off, 64);
        qs[u] += __shfl_xor(qs[u], off, 64);
        ks[u] += __shfl_xor(ks[u], off, 64);
      }
    }

    if ((lane & 7) == 0) {
      const int h = lane >> 3;
#pragma unroll
      for (int u = 0; u < 4; ++u) {
        const float denom = fmaxf(sqrtf(qs[u]) * sqrtf(ks[u]), EPSV);
        sA[wave * 16 + t + u][h] = fmaxf(dt[u] / denom, 0.0f);
      }
    }
  }
  __syncthreads();

  // Coalesced store of attn*roi: 1024 floats per block, 2 per thread.
  {
    const size_t outbase = (size_t)bi * NUMR * HH;
    const int roibase = bi * NUMR;
#pragma unroll
    for (int idx = threadIdx.x; idx < NUMR * HH; idx += 512) {
      out[outbase + idx] = sA[idx >> 3][idx & 7] * roi[roibase + (idx >> 3)];
    }
  }

  // top-4 over j for head h = wave (on PURE attn from LDS). lane holds
  // j=lane and j=lane+64. Tie-break: equal value -> lower index wins
  // (matches jax.lax.top_k stable-descending index set).
  float v0 = sA[lane][wave];
  float v1 = sA[lane + 64][wave];
#pragma unroll
  for (int rnd = 0; rnd < 4; ++rnd) {
    float bv;
    int bj;
    if (v1 > v0) { bv = v1; bj = lane + 64; } else { bv = v0; bj = lane; }
#pragma unroll
    for (int off = 1; off < 64; off <<= 1) {
      const float ov = __shfl_xor(bv, off, 64);
      const int   oj = __shfl_xor(bj, off, 64);
      if (ov > bv || (ov == bv && oj < bj)) { bv = ov; bj = oj; }
    }
    if (bj == lane)           v0 = -1.0f;
    else if (bj == lane + 64) v1 = -1.0f;
    if (lane == 0) colmask[bj] = 1.0f;  // racing identical stores: benign
  }
}

// ---------------------------------------------------------------------------
// Kernel B: out[b,i,j,h] *= colmask[j]  (roi already folded in by kernel A)
// One thread per (b,i,j): 8 head values as 2 x float4.
// ---------------------------------------------------------------------------
__global__ __launch_bounds__(256) void apply_kernel(
    float* __restrict__ out, const float* __restrict__ colmask) {
  const int t = blockIdx.x * blockDim.x + threadIdx.x;  // (b*num+i)*num+j
  const float s = colmask[t & (NUMR - 1)];
  float4* p = (float4*)(out + (size_t)t * 8);
  float4 x0 = p[0], x1 = p[1];
  x0.x *= s; x0.y *= s; x0.z *= s; x0.w *= s;
  x1.x *= s; x1.y *= s; x1.z *= s; x1.w *= s;
  p[0] = x0;
  p[1] = x1;
}

extern "C" void kernel_launch(void* const* d_in, const int* in_sizes, int n_in,
                              void* d_out, int out_size, void* d_ws, size_t ws_size,
                              hipStream_t stream) {
  const float* q   = (const float*)d_in[0];  // (B, num, num, C) fp32
  const float* k   = (const float*)d_in[1];  // (B, num, num, C) fp32
  const float* roi = (const float*)d_in[2];  // (B, num, num)    fp32
  float* out = (float*)d_out;                // (B, num, num, H) fp32
  float* colmask = (float*)d_ws;             // 128 floats

  // zero the 128-entry column mask (ws is poisoned 0xAA before every launch)
  hipMemsetAsync(colmask, 0, NUMR * sizeof(float), stream);

  // Kernel A: one block per (b,i) -> 1024 blocks x 512 threads
  cos_topk_kernel<<<B_SZ * NUMR, 512, 0, stream>>>(q, k, roi, out, colmask);

  // Kernel B: B*num*num threads -> 512 blocks x 256
  apply_kernel<<<(B_SZ * L_SZ) / 256, 256, 0, stream>>>(out, colmask);
}